// Round 2
// baseline (2464.749 us; speedup 1.0000x reference)
//
#include <hip/hip_runtime.h>
#include <hip/hip_bf16.h>

typedef _Float16 h2 __attribute__((ext_vector_type(2)));

#define NTOT  16384
#define NN    70
#define EE    3
#define SS    10
#define STEPS 5
#define NB    8
#define NPAIR (NB*NN)   // 560
#define TPB   576       // 9 waves
#define ASTR  214       // A row stride (fp16 elems) = 107 words, odd -> conflict-free lane reads
#define PT    72        // propT m-stride (fp16 elems)

// weight offsets (floats) inside g_w
#define OFF_WIN 0
#define OFF_BIN 300
#define OFF_WR  330
#define OFF_BR  530
#define OFF_WZ  540
#define OFF_BZ  740
#define OFF_WH  750
#define OFF_BH  950
#define OFF_WO1 960
#define OFF_BO1 1070
#define OFF_WO2 1080
#define OFF_BO2 1090
#define NWTOT   1091

__device__ float g_w[NWTOT + 1];
__device__ int   g_flag;

#if __has_builtin(__builtin_amdgcn_fdot2)
#define FDOT2(a,q,c) __builtin_amdgcn_fdot2((a),(q),(c),false)
#else
#define FDOT2(a,q,c) ((c) + (float)(a)[0]*(float)(q)[0] + (float)(a)[1]*(float)(q)[1])
#endif

__device__ __forceinline__ float fast_sigmoid(float x) {
    return __builtin_amdgcn_rcpf(1.0f + __expf(-x));
}
__device__ __forceinline__ float fast_tanh(float x) {
    float ax = fabsf(x);
    float e  = __expf(-2.0f * ax);
    float t  = (1.0f - e) * __builtin_amdgcn_rcpf(1.0f + e);
    return copysignf(t, x);
}

struct __align__(16) Smem {
    _Float16 A[NN*ASTR];        // 29960 B, A as fp16: [n][e*70+m]
    _Float16 propT[NB*SS*PT];   // 11520 B, prop transposed: [i][s][m]
};
// ~41.5 KB -> 3 blocks/CU

// ---- prep: probe dtype once, convert all weights to fp32 in g_w ----
__global__ void prep_kernel(const void* annv,
    const void* s0, const void* s1, const void* s2, const void* s3,
    const void* s4, const void* s5, const void* s6, const void* s7,
    const void* s8, const void* s9, const void* s10, const void* s11)
{
    __shared__ int sflag;
    if (threadIdx.x == 0) {
        const unsigned short* u = (const unsigned short*)annv;
        int good = 0;
        for (int k = 0; k < 128; ++k) {
            unsigned short bb = u[k];
            int ex = (bb >> 7) & 0xFF;
            if (bb == 0 || (ex >= 101 && ex <= 131)) ++good;
        }
        sflag = (good >= 112) ? 1 : 0;
        g_flag = sflag;
    }
    __syncthreads();
    const int f = sflag;
    const void* srcs[12] = {s0,s1,s2,s3,s4,s5,s6,s7,s8,s9,s10,s11};
    const int offs[12] = {OFF_WIN,OFF_BIN,OFF_WR,OFF_BR,OFF_WZ,OFF_BZ,
                          OFF_WH,OFF_BH,OFF_WO1,OFF_BO1,OFF_WO2,OFF_BO2};
    const int cnts[12] = {300,30,200,10,200,10,200,10,110,10,10,1};
    for (int a = 0; a < 12; ++a)
        for (int k = threadIdx.x; k < cnts[a]; k += blockDim.x)
            g_w[offs[a] + k] = f ? (float)((const __hip_bfloat16*)srcs[a])[k]
                                 : ((const float*)srcs[a])[k];
}

template<typename T>
__device__ __forceinline__ void run_impl(const void* annv, const void* Av,
                                         void* outv, Smem& sm)
{
    const T* ann_g = (const T*)annv;
    const T* A_g   = (const T*)Av;
    T* out_g       = (T*)outv;
    const int tid = threadIdx.x;
    const int blk = blockIdx.x;

    // ---- stage A into LDS as fp16: global A[n][j] (j = e*70+m) -> sm.A[n*ASTR + j]
    for (int idx = tid; idx < NN*NN*EE; idx += TPB) {
        const int n2 = idx / (NN*EE);
        const int j  = idx - n2*(NN*EE);
        sm.A[n2*ASTR + j] = (_Float16)(float)A_g[idx];
    }

    const int p     = tid;
    const bool act  = (p < NPAIR);
    const int i_loc = p / NN;
    const int n     = p - i_loc*NN;
    const int b     = blk*NB + i_loc;

    float ann = 0.f;
    float pr[SS];
    #pragma unroll
    for (int s = 0; s < SS; ++s) pr[s] = 0.f;
    if (act) {
        ann   = (float)ann_g[b*NN + n];
        pr[0] = ann;
        _Float16* pt = &sm.propT[i_loc*SS*PT + n];
        #pragma unroll
        for (int s = 0; s < SS; ++s) pt[s*PT] = (s == 0) ? (_Float16)ann : (_Float16)0.f;
    }
    __syncthreads();

    // ---- per-edge A row-sums (bias through aggregation), once
    float rs0 = 0.f, rs1 = 0.f, rs2 = 0.f;
    const _Float16* Arow = &sm.A[n*ASTR];
    if (act) {
        const h2 one2 = { (_Float16)1.f, (_Float16)1.f };
        #pragma unroll 5
        for (int k = 0; k < 35; ++k) {
            h2 a0 = *(const h2*)(Arow + 2*k);
            h2 a1 = *(const h2*)(Arow + 70 + 2*k);
            h2 a2 = *(const h2*)(Arow + 140 + 2*k);
            rs0 = FDOT2(a0, one2, rs0);
            rs1 = FDOT2(a1, one2, rs1);
            rs2 = FDOT2(a2, one2, rs2);
        }
    }

    #pragma unroll 1
    for (int step = 0; step < STEPS; ++step) {
        float a_in[SS];
        if (act) {
            float P0[SS], P1[SS], P2[SS];
            #pragma unroll
            for (int s = 0; s < SS; ++s) { P0[s]=0.f; P1[s]=0.f; P2[s]=0.f; }
            const _Float16* Qb = &sm.propT[i_loc*SS*PT];
            #pragma unroll 5
            for (int k = 0; k < 35; ++k) {
                h2 a0 = *(const h2*)(Arow + 2*k);
                h2 a1 = *(const h2*)(Arow + 70 + 2*k);
                h2 a2 = *(const h2*)(Arow + 140 + 2*k);
                #pragma unroll
                for (int s = 0; s < SS; ++s) {
                    h2 q = *(const h2*)(Qb + s*PT + 2*k);
                    P0[s] = FDOT2(a0, q, P0[s]);
                    P1[s] = FDOT2(a1, q, P1[s]);
                    P2[s] = FDOT2(a2, q, P2[s]);
                }
            }
            // transform: a_in[s] = sum_e (W_in[e] @ P_e)[s] + (rowsum_e * b_in[e])[s]
            #pragma unroll
            for (int s = 0; s < SS; ++s) {
                float acc = rs0*g_w[OFF_BIN+s] + rs1*g_w[OFF_BIN+SS+s] + rs2*g_w[OFF_BIN+2*SS+s];
                #pragma unroll
                for (int t = 0; t < SS; ++t) {
                    acc += g_w[OFF_WIN +   0 + s*SS + t] * P0[t];
                    acc += g_w[OFF_WIN + 100 + s*SS + t] * P1[t];
                    acc += g_w[OFF_WIN + 200 + s*SS + t] * P2[t];
                }
                a_in[s] = acc;
            }
            // gates (fp32, weights via uniform scalar loads)
            float rv[SS], hh[SS], zv[SS];
            #pragma unroll
            for (int s = 0; s < SS; ++s) {
                float acc = g_w[OFF_BR+s];
                #pragma unroll
                for (int d = 0; d < SS; ++d) acc += a_in[d]*g_w[OFF_WR + s*2*SS + d];
                #pragma unroll
                for (int d = 0; d < SS; ++d) acc += pr[d]*g_w[OFF_WR + s*2*SS + SS + d];
                rv[s] = fast_sigmoid(acc);
            }
            #pragma unroll
            for (int s = 0; s < SS; ++s) rv[s] *= pr[s];   // r * prop
            #pragma unroll
            for (int s = 0; s < SS; ++s) {
                float acc = g_w[OFF_BH+s];
                #pragma unroll
                for (int d = 0; d < SS; ++d) acc += a_in[d]*g_w[OFF_WH + s*2*SS + d];
                #pragma unroll
                for (int d = 0; d < SS; ++d) acc += rv[d]*g_w[OFF_WH + s*2*SS + SS + d];
                hh[s] = fast_tanh(acc);
            }
            #pragma unroll
            for (int s = 0; s < SS; ++s) {
                float acc = g_w[OFF_BZ+s];
                #pragma unroll
                for (int d = 0; d < SS; ++d) acc += a_in[d]*g_w[OFF_WZ + s*2*SS + d];
                #pragma unroll
                for (int d = 0; d < SS; ++d) acc += pr[d]*g_w[OFF_WZ + s*2*SS + SS + d];
                zv[s] = fast_sigmoid(acc);
            }
            #pragma unroll
            for (int s = 0; s < SS; ++s) pr[s] += zv[s]*(hh[s]-pr[s]);
        }
        __syncthreads();   // all propT reads done before overwrite
        if (act) {
            _Float16* pt = &sm.propT[i_loc*SS*PT + n];
            #pragma unroll
            for (int s = 0; s < SS; ++s) pt[s*PT] = (_Float16)pr[s];
        }
        __syncthreads();   // new propT visible
    }

    // ---- epilogue: out = tanh([prop, ann] @ Wo1^T + bo1) @ Wo2^T + bo2
    if (act) {
        float o = g_w[OFF_BO2];
        #pragma unroll
        for (int s = 0; s < SS; ++s) {
            float acc = g_w[OFF_BO1+s] + ann*g_w[OFF_WO1 + s*(SS+1) + SS];
            #pragma unroll
            for (int d = 0; d < SS; ++d) acc += pr[d]*g_w[OFF_WO1 + s*(SS+1) + d];
            o += fast_tanh(acc) * g_w[OFF_WO2 + s];
        }
        out_g[b*NN + n] = (T)o;
    }
}

__global__ __launch_bounds__(TPB, 7)
void ggnn_kernel(const void* annv, const void* Av, void* outv)
{
    __shared__ Smem sm;
    if (g_flag)
        run_impl<__hip_bfloat16>(annv, Av, outv, sm);
    else
        run_impl<float>(annv, Av, outv, sm);
}

extern "C" void kernel_launch(void* const* d_in, const int* in_sizes, int n_in,
                              void* d_out, int out_size, void* d_ws, size_t ws_size,
                              hipStream_t stream) {
    (void)in_sizes; (void)n_in; (void)out_size; (void)d_ws; (void)ws_size;
    hipLaunchKernelGGL(prep_kernel, dim3(1), dim3(256), 0, stream,
        d_in[0], d_in[2], d_in[3], d_in[4], d_in[5], d_in[6], d_in[7],
        d_in[8], d_in[9], d_in[10], d_in[11], d_in[12], d_in[13]);
    hipLaunchKernelGGL(ggnn_kernel, dim3(NTOT/NB), dim3(TPB), 0, stream,
        d_in[0], d_in[1], d_out);
}

// Round 3
// 1871.572 us; speedup vs baseline: 1.3169x; 1.3169x over previous
//
#include <hip/hip_runtime.h>
#include <hip/hip_bf16.h>

typedef _Float16 h2 __attribute__((ext_vector_type(2)));
typedef _Float16 h4 __attribute__((ext_vector_type(4)));
typedef _Float16 h8 __attribute__((ext_vector_type(8)));

#define NTOT  16384
#define NN    70
#define EE    3
#define SS    10
#define STEPS 5
#define NB    7
#define NPAIR (NB*NN)               // 490 active of 512
#define TPB   512                   // 8 waves
#define NBLK  ((NTOT + NB - 1)/NB)  // 2341
#define ASTR  214  // A row stride in fp16 (107 dwords, odd multiple -> max 2-way bank alias = free)
#define PPK   24   // pp k-stride in fp16 (48 B, multiple of 16 B for b128 reads)
#define PPG   (35*PPK)              // per-graph pp: 840 fp16 = 1680 B

// weight offsets (floats) inside g_w
#define OFF_WIN 0
#define OFF_BIN 300
#define OFF_WR  330
#define OFF_BR  530
#define OFF_WZ  540
#define OFF_BZ  740
#define OFF_WH  750
#define OFF_BH  950
#define OFF_WO1 960
#define OFF_BO1 1070
#define OFF_WO2 1080
#define OFF_BO2 1090
#define NWTOT   1091

__device__ float g_w[NWTOT + 1];
__device__ int   g_flag;

#if __has_builtin(__builtin_amdgcn_fdot2)
#define FDOT2(a,q,c) __builtin_amdgcn_fdot2((a),(q),(c),false)
#else
#define FDOT2(a,q,c) ((c) + (float)(a)[0]*(float)(q)[0] + (float)(a)[1]*(float)(q)[1])
#endif

__device__ __forceinline__ float fast_sigmoid(float x) {
    return __builtin_amdgcn_rcpf(1.0f + __expf(-x));
}
__device__ __forceinline__ float fast_tanh(float x) {
    float ax = fabsf(x);
    float e  = __expf(-2.0f * ax);
    float t  = (1.0f - e) * __builtin_amdgcn_rcpf(1.0f + e);
    return copysignf(t, x);
}

struct __align__(16) Smem {
    _Float16 A[NN*ASTR + 4];   // 29968 B (padded so pp is 16B-aligned)
    _Float16 pp[NB*PPG];       // 11760 B, pair-interleaved propT:
                               // pp[i][k][s] = (prop[2k][s], prop[2k+1][s]) as h2
};
// ~41.7 KB -> 2-3 blocks/CU

// ---- prep: probe dtype once, convert all weights to fp32 in g_w ----
__global__ void prep_kernel(const void* annv,
    const void* s0, const void* s1, const void* s2, const void* s3,
    const void* s4, const void* s5, const void* s6, const void* s7,
    const void* s8, const void* s9, const void* s10, const void* s11)
{
    __shared__ int sflag;
    if (threadIdx.x == 0) {
        const unsigned short* u = (const unsigned short*)annv;
        int good = 0;
        for (int k = 0; k < 128; ++k) {
            unsigned short bb = u[k];
            int ex = (bb >> 7) & 0xFF;
            if (bb == 0 || (ex >= 101 && ex <= 131)) ++good;
        }
        sflag = (good >= 112) ? 1 : 0;
        g_flag = sflag;
    }
    __syncthreads();
    const int f = sflag;
    const void* srcs[12] = {s0,s1,s2,s3,s4,s5,s6,s7,s8,s9,s10,s11};
    const int offs[12] = {OFF_WIN,OFF_BIN,OFF_WR,OFF_BR,OFF_WZ,OFF_BZ,
                          OFF_WH,OFF_BH,OFF_WO1,OFF_BO1,OFF_WO2,OFF_BO2};
    const int cnts[12] = {300,30,200,10,200,10,200,10,110,10,10,1};
    for (int a = 0; a < 12; ++a)
        for (int k = threadIdx.x; k < cnts[a]; k += blockDim.x)
            g_w[offs[a] + k] = f ? (float)((const __hip_bfloat16*)srcs[a])[k]
                                 : ((const float*)srcs[a])[k];
}

template<typename T>
__device__ __forceinline__ void run_impl(const void* annv, const void* Av,
                                         void* outv, Smem& sm)
{
    const T* ann_g = (const T*)annv;
    const T* A_g   = (const T*)Av;
    T* out_g       = (T*)outv;
    const int tid = threadIdx.x;
    const int blk = blockIdx.x;

    // ---- stage A into LDS as fp16: global A[n][j] (j = e*70+m) -> sm.A[n*ASTR + j]
    for (int idx = tid; idx < NN*NN*EE; idx += TPB) {
        const int n2 = idx / (NN*EE);
        const int j  = idx - n2*(NN*EE);
        sm.A[n2*ASTR + j] = (_Float16)(float)A_g[idx];
    }

    const int p     = tid;
    const int i_loc = p / NN;
    const int n     = p - i_loc*NN;
    const int b     = blk*NB + i_loc;
    const bool act  = (p < NPAIR) && (b < NTOT);

    float ann = 0.f;
    float pr[SS];
    #pragma unroll
    for (int s = 0; s < SS; ++s) pr[s] = 0.f;
    if (act) {
        ann   = (float)ann_g[b*NN + n];
        pr[0] = ann;
        // init pp: thread n writes (prop[n][s]) into half (n&1) of pp[i][n>>1][s]
        _Float16* pw = &sm.pp[i_loc*PPG + (n>>1)*PPK + (n&1)];
        #pragma unroll
        for (int s = 0; s < SS; ++s) pw[2*s] = (s == 0) ? (_Float16)ann : (_Float16)0.f;
    }
    __syncthreads();

    // ---- per-edge A row-sums (bias through aggregation), once
    float rs0 = 0.f, rs1 = 0.f, rs2 = 0.f;
    const _Float16* Arow = &sm.A[n*ASTR];
    if (act) {
        const h2 one2 = { (_Float16)1.f, (_Float16)1.f };
        #pragma unroll 5
        for (int k = 0; k < 35; ++k) {
            h2 a0 = *(const h2*)(Arow + 2*k);
            h2 a1 = *(const h2*)(Arow + 70 + 2*k);
            h2 a2 = *(const h2*)(Arow + 140 + 2*k);
            rs0 = FDOT2(a0, one2, rs0);
            rs1 = FDOT2(a1, one2, rs1);
            rs2 = FDOT2(a2, one2, rs2);
        }
    }

    #pragma unroll 1
    for (int step = 0; step < STEPS; ++step) {
        if (act) {
            float P0[SS], P1[SS], P2[SS];
            #pragma unroll
            for (int s = 0; s < SS; ++s) { P0[s]=0.f; P1[s]=0.f; P2[s]=0.f; }
            const _Float16* ppg = &sm.pp[i_loc*PPG];
            #pragma unroll 5
            for (int k = 0; k < 35; ++k) {
                h2 a0 = *(const h2*)(Arow + 2*k);
                h2 a1 = *(const h2*)(Arow + 70 + 2*k);
                h2 a2 = *(const h2*)(Arow + 140 + 2*k);
                h8 t0 = *(const h8*)(ppg + k*PPK);        // s0..s3 pairs
                h8 t1 = *(const h8*)(ppg + k*PPK + 8);    // s4..s7 pairs
                h4 t2 = *(const h4*)(ppg + k*PPK + 16);   // s8..s9 pairs
                h2 qq[SS];
                qq[0]=(h2){t0[0],t0[1]}; qq[1]=(h2){t0[2],t0[3]};
                qq[2]=(h2){t0[4],t0[5]}; qq[3]=(h2){t0[6],t0[7]};
                qq[4]=(h2){t1[0],t1[1]}; qq[5]=(h2){t1[2],t1[3]};
                qq[6]=(h2){t1[4],t1[5]}; qq[7]=(h2){t1[6],t1[7]};
                qq[8]=(h2){t2[0],t2[1]}; qq[9]=(h2){t2[2],t2[3]};
                #pragma unroll
                for (int s = 0; s < SS; ++s) {
                    P0[s] = FDOT2(a0, qq[s], P0[s]);
                    P1[s] = FDOT2(a1, qq[s], P1[s]);
                    P2[s] = FDOT2(a2, qq[s], P2[s]);
                }
            }
            // transform: a_in[s] = sum_e (W_in[e] @ P_e)[s] + (rowsum_e * b_in[e])[s]
            float a_in[SS];
            #pragma unroll
            for (int s = 0; s < SS; ++s) {
                float acc = rs0*g_w[OFF_BIN+s] + rs1*g_w[OFF_BIN+SS+s] + rs2*g_w[OFF_BIN+2*SS+s];
                #pragma unroll
                for (int t = 0; t < SS; ++t) {
                    acc += g_w[OFF_WIN +   0 + s*SS + t] * P0[t];
                    acc += g_w[OFF_WIN + 100 + s*SS + t] * P1[t];
                    acc += g_w[OFF_WIN + 200 + s*SS + t] * P2[t];
                }
                a_in[s] = acc;
            }
            // gates (fp32, weights via uniform scalar loads)
            float rv[SS], hh[SS], zv[SS];
            #pragma unroll
            for (int s = 0; s < SS; ++s) {
                float acc = g_w[OFF_BR+s];
                #pragma unroll
                for (int d = 0; d < SS; ++d) acc += a_in[d]*g_w[OFF_WR + s*2*SS + d];
                #pragma unroll
                for (int d = 0; d < SS; ++d) acc += pr[d]*g_w[OFF_WR + s*2*SS + SS + d];
                rv[s] = fast_sigmoid(acc);
            }
            #pragma unroll
            for (int s = 0; s < SS; ++s) rv[s] *= pr[s];   // r * prop
            #pragma unroll
            for (int s = 0; s < SS; ++s) {
                float acc = g_w[OFF_BH+s];
                #pragma unroll
                for (int d = 0; d < SS; ++d) acc += a_in[d]*g_w[OFF_WH + s*2*SS + d];
                #pragma unroll
                for (int d = 0; d < SS; ++d) acc += rv[d]*g_w[OFF_WH + s*2*SS + SS + d];
                hh[s] = fast_tanh(acc);
            }
            #pragma unroll
            for (int s = 0; s < SS; ++s) {
                float acc = g_w[OFF_BZ+s];
                #pragma unroll
                for (int d = 0; d < SS; ++d) acc += a_in[d]*g_w[OFF_WZ + s*2*SS + d];
                #pragma unroll
                for (int d = 0; d < SS; ++d) acc += pr[d]*g_w[OFF_WZ + s*2*SS + SS + d];
                zv[s] = fast_sigmoid(acc);
            }
            #pragma unroll
            for (int s = 0; s < SS; ++s) pr[s] += zv[s]*(hh[s]-pr[s]);
        }
        __syncthreads();   // all pp reads done before overwrite
        if (act) {
            _Float16* pw = &sm.pp[i_loc*PPG + (n>>1)*PPK + (n&1)];
            #pragma unroll
            for (int s = 0; s < SS; ++s) pw[2*s] = (_Float16)pr[s];
        }
        __syncthreads();   // new pp visible
    }

    // ---- epilogue: out = tanh([prop, ann] @ Wo1^T + bo1) @ Wo2^T + bo2
    if (act) {
        float o = g_w[OFF_BO2];
        #pragma unroll
        for (int s = 0; s < SS; ++s) {
            float acc = g_w[OFF_BO1+s] + ann*g_w[OFF_WO1 + s*(SS+1) + SS];
            #pragma unroll
            for (int d = 0; d < SS; ++d) acc += pr[d]*g_w[OFF_WO1 + s*(SS+1) + d];
            o += fast_tanh(acc) * g_w[OFF_WO2 + s];
        }
        out_g[b*NN + n] = (T)o;
    }
}

__global__ __launch_bounds__(TPB, 5)   // 102-VGPR cap: live set ~85, must not spill
void ggnn_kernel(const void* annv, const void* Av, void* outv)
{
    __shared__ Smem sm;
    if (g_flag)
        run_impl<__hip_bfloat16>(annv, Av, outv, sm);
    else
        run_impl<float>(annv, Av, outv, sm);
}

extern "C" void kernel_launch(void* const* d_in, const int* in_sizes, int n_in,
                              void* d_out, int out_size, void* d_ws, size_t ws_size,
                              hipStream_t stream) {
    (void)in_sizes; (void)n_in; (void)out_size; (void)d_ws; (void)ws_size;
    hipLaunchKernelGGL(prep_kernel, dim3(1), dim3(256), 0, stream,
        d_in[0], d_in[2], d_in[3], d_in[4], d_in[5], d_in[6], d_in[7],
        d_in[8], d_in[9], d_in[10], d_in[11], d_in[12], d_in[13]);
    hipLaunchKernelGGL(ggnn_kernel, dim3(NBLK), dim3(TPB), 0, stream,
        d_in[0], d_in[1], d_out);
}

// Round 4
// 1064.833 us; speedup vs baseline: 2.3147x; 1.7576x over previous
//
#include <hip/hip_runtime.h>
#include <hip/hip_bf16.h>

typedef _Float16 h2 __attribute__((ext_vector_type(2)));

#define NTOT  16384
#define NN    70
#define EE    3
#define SS    10
#define STEPS 5
#define NB    7
#define NPAIR (NB*NN)               // 490 active of 512
#define TPB   512                   // 8 waves
#define NBLK  ((NTOT + NB - 1)/NB)  // 2341
#define JTOT  210                   // E*N
#define ASTR  220                   // A row stride in fp16 (440 B, 8B-aligned rows)
#define UG    2120                  // U per-graph size in fp16: 106 k-rows * 20
#define UQ    265                   // U per-graph size in uint4 (4240 B / 16)

// weight offsets (floats) inside g_w
#define OFF_WIN 0
#define OFF_BIN 300
#define OFF_WR  330
#define OFF_BR  530
#define OFF_WZ  540
#define OFF_BZ  740
#define OFF_WH  750
#define OFF_BH  950
#define OFF_WO1 960
#define OFF_BO1 1070
#define OFF_WO2 1080
#define OFF_BO2 1090
#define NWTOT   1091

__device__ float g_w[NWTOT + 1];
__device__ int   g_flag;

#if __has_builtin(__builtin_amdgcn_fdot2)
#define FDOT2(a,q,c) __builtin_amdgcn_fdot2((a),(q),(c),false)
#else
#define FDOT2(a,q,c) ((c) + (float)(a)[0]*(float)(q)[0] + (float)(a)[1]*(float)(q)[1])
#endif

__device__ __forceinline__ h2 h2_of(unsigned x) {
    union { unsigned u; h2 h; } c; c.u = x; return c.h;
}
__device__ __forceinline__ float fast_sigmoid(float x) {
    return __builtin_amdgcn_rcpf(1.0f + __expf(-x));
}
__device__ __forceinline__ float fast_tanh(float x) {
    float ax = fabsf(x);
    float e  = __expf(-2.0f * ax);
    float t  = (1.0f - e) * __builtin_amdgcn_rcpf(1.0f + e);
    return copysignf(t, x);
}

struct __align__(16) Smem {
    _Float16 A[NN*ASTR];   // 30800 B: A[n][j], j<212 used (210,211 zero), pad to 220
    _Float16 U[NB*UG];     // 29680 B: pair-interleaved ins:
                           //   U[g][k][s] = (ins[2k][s], ins[2k+1][s]); k=105 row zero
};
// 60480 B -> 2 blocks/CU

// ---- prep: probe dtype once, convert all weights to fp32 in g_w ----
__global__ void prep_kernel(const void* annv,
    const void* s0, const void* s1, const void* s2, const void* s3,
    const void* s4, const void* s5, const void* s6, const void* s7,
    const void* s8, const void* s9, const void* s10, const void* s11)
{
    __shared__ int sflag;
    if (threadIdx.x == 0) {
        const unsigned short* u = (const unsigned short*)annv;
        int good = 0;
        for (int k = 0; k < 128; ++k) {
            unsigned short bb = u[k];
            int ex = (bb >> 7) & 0xFF;
            if (bb == 0 || (ex >= 101 && ex <= 131)) ++good;
        }
        sflag = (good >= 112) ? 1 : 0;
        g_flag = sflag;
    }
    __syncthreads();
    const int f = sflag;
    const void* srcs[12] = {s0,s1,s2,s3,s4,s5,s6,s7,s8,s9,s10,s11};
    const int offs[12] = {OFF_WIN,OFF_BIN,OFF_WR,OFF_BR,OFF_WZ,OFF_BZ,
                          OFF_WH,OFF_BH,OFF_WO1,OFF_BO1,OFF_WO2,OFF_BO2};
    const int cnts[12] = {300,30,200,10,200,10,200,10,110,10,10,1};
    for (int a = 0; a < 12; ++a)
        for (int k = threadIdx.x; k < cnts[a]; k += blockDim.x)
            g_w[offs[a] + k] = f ? (float)((const __hip_bfloat16*)srcs[a])[k]
                                 : ((const float*)srcs[a])[k];
}

template<typename T>
__device__ __forceinline__ void run_impl(const void* annv, const void* Av,
                                         void* outv, Smem& sm)
{
    const T* ann_g = (const T*)annv;
    const T* A_g   = (const T*)Av;
    T* out_g       = (T*)outv;
    const int tid = threadIdx.x;
    const int blk = blockIdx.x;
    const float* __restrict__ gw = g_w;

    // ---- zero pads: A[n][210..219], U pad row k=105 per graph
    for (int idx = tid; idx < NN*10; idx += TPB) {
        const int n2 = idx / 10, c = idx - n2*10;
        sm.A[n2*ASTR + JTOT + c] = (_Float16)0.f;
    }
    for (int idx = tid; idx < NB*20; idx += TPB) {
        const int g = idx / 20, c = idx - g*20;
        sm.U[g*UG + 105*20 + c] = (_Float16)0.f;
    }
    // ---- stage A into LDS as fp16: A[n][j] -> sm.A[n*ASTR + j]
    for (int idx = tid; idx < NN*JTOT; idx += TPB) {
        const int n2 = idx / JTOT;
        const int j  = idx - n2*JTOT;
        sm.A[n2*ASTR + j] = (_Float16)(float)A_g[idx];
    }

    const int p     = tid;
    const int i0    = p / NN;               // 0..7
    const int n     = p - i0*NN;            // 0..69
    const int b     = blk*NB + i0;
    const bool act  = (p < NPAIR) && (b < NTOT);
    const int il    = act ? i0 : 0;         // clamp for safe addressing

    float ann = 0.f;
    float pr[SS];
    #pragma unroll
    for (int s = 0; s < SS; ++s) pr[s] = 0.f;
    if (act) { ann = (float)ann_g[b*NN + n]; pr[0] = ann; }
    __syncthreads();

    const _Float16* Arow = &sm.A[n*ASTR];
    const uint2* Ap = (const uint2*)Arow;           // A[n][4t..4t+3] per read
    const uint4* Uq = (const uint4*)&sm.U[il*UG];   // 5 per pair of k-rows

    #pragma unroll 1
    for (int step = 0; step < STEPS; ++step) {
        // ---- U-build: thread n writes ins rows j=e*70+n (uniform compute, guarded store)
        #pragma unroll
        for (int e = 0; e < EE; ++e) {
            _Float16* uw = &sm.U[il*UG + (e*35 + (n>>1))*20 + (n&1)];
            #pragma unroll
            for (int s = 0; s < SS; ++s) {
                float u = gw[OFF_BIN + e*SS + s];
                #pragma unroll
                for (int t = 0; t < SS; ++t)
                    u += gw[OFF_WIN + e*100 + s*SS + t] * pr[t];
                if (act) uw[2*s] = (_Float16)u;
            }
        }
        __syncthreads();

        // ---- a_in = A_row . U   (210-long dot, fdot2, 10 accumulators)
        float ai[SS];
        #pragma unroll
        for (int s = 0; s < SS; ++s) ai[s] = 0.f;
        #pragma unroll 1
        for (int t = 0; t < 53; ++t) {
            const uint2 a  = Ap[t];
            const uint4 L0 = Uq[5*t+0];
            const uint4 L1 = Uq[5*t+1];
            const uint4 L2 = Uq[5*t+2];
            const uint4 L3 = Uq[5*t+3];
            const uint4 L4 = Uq[5*t+4];
            const h2 a01 = h2_of(a.x), a23 = h2_of(a.y);
            ai[0] = FDOT2(a01, h2_of(L0.x), ai[0]);
            ai[1] = FDOT2(a01, h2_of(L0.y), ai[1]);
            ai[2] = FDOT2(a01, h2_of(L0.z), ai[2]);
            ai[3] = FDOT2(a01, h2_of(L0.w), ai[3]);
            ai[4] = FDOT2(a01, h2_of(L1.x), ai[4]);
            ai[5] = FDOT2(a01, h2_of(L1.y), ai[5]);
            ai[6] = FDOT2(a01, h2_of(L1.z), ai[6]);
            ai[7] = FDOT2(a01, h2_of(L1.w), ai[7]);
            ai[8] = FDOT2(a01, h2_of(L2.x), ai[8]);
            ai[9] = FDOT2(a01, h2_of(L2.y), ai[9]);
            ai[0] = FDOT2(a23, h2_of(L2.z), ai[0]);
            ai[1] = FDOT2(a23, h2_of(L2.w), ai[1]);
            ai[2] = FDOT2(a23, h2_of(L3.x), ai[2]);
            ai[3] = FDOT2(a23, h2_of(L3.y), ai[3]);
            ai[4] = FDOT2(a23, h2_of(L3.z), ai[4]);
            ai[5] = FDOT2(a23, h2_of(L3.w), ai[5]);
            ai[6] = FDOT2(a23, h2_of(L4.x), ai[6]);
            ai[7] = FDOT2(a23, h2_of(L4.y), ai[7]);
            ai[8] = FDOT2(a23, h2_of(L4.z), ai[8]);
            ai[9] = FDOT2(a23, h2_of(L4.w), ai[9]);
        }

        // ---- gates (fp32, weights via uniform scalar loads)
        float rp[SS], hh[SS];
        #pragma unroll
        for (int s = 0; s < SS; ++s) {
            float acc = gw[OFF_BR+s];
            #pragma unroll
            for (int d = 0; d < SS; ++d) acc += ai[d]*gw[OFF_WR + s*2*SS + d];
            #pragma unroll
            for (int d = 0; d < SS; ++d) acc += pr[d]*gw[OFF_WR + s*2*SS + SS + d];
            rp[s] = fast_sigmoid(acc) * pr[s];   // r * prop
        }
        #pragma unroll
        for (int s = 0; s < SS; ++s) {
            float acc = gw[OFF_BH+s];
            #pragma unroll
            for (int d = 0; d < SS; ++d) acc += ai[d]*gw[OFF_WH + s*2*SS + d];
            #pragma unroll
            for (int d = 0; d < SS; ++d) acc += rp[d]*gw[OFF_WH + s*2*SS + SS + d];
            hh[s] = fast_tanh(acc);
        }
        #pragma unroll
        for (int s = 0; s < SS; ++s) {
            float acc = gw[OFF_BZ+s];
            #pragma unroll
            for (int d = 0; d < SS; ++d) acc += ai[d]*gw[OFF_WZ + s*2*SS + d];
            #pragma unroll
            for (int d = 0; d < SS; ++d) acc += pr[d]*gw[OFF_WZ + s*2*SS + SS + d];
            const float z = fast_sigmoid(acc);
            pr[s] += z*(hh[s]-pr[s]);
        }
        __syncthreads();   // all U reads done before next step's U-build overwrites
    }

    // ---- epilogue: out = tanh([prop, ann] @ Wo1^T + bo1) @ Wo2^T + bo2
    if (act) {
        float o = gw[OFF_BO2];
        #pragma unroll
        for (int s = 0; s < SS; ++s) {
            float acc = gw[OFF_BO1+s] + ann*gw[OFF_WO1 + s*(SS+1) + SS];
            #pragma unroll
            for (int d = 0; d < SS; ++d) acc += pr[d]*gw[OFF_WO1 + s*(SS+1) + d];
            o += fast_tanh(acc) * gw[OFF_WO2 + s];
        }
        out_g[b*NN + n] = (T)o;
    }
}

__global__ __launch_bounds__(TPB, 3)   // 170-VGPR cap: live ~60, do NOT spill
void ggnn_kernel(const void* annv, const void* Av, void* outv)
{
    __shared__ Smem sm;
    if (g_flag)
        run_impl<__hip_bfloat16>(annv, Av, outv, sm);
    else
        run_impl<float>(annv, Av, outv, sm);
}

extern "C" void kernel_launch(void* const* d_in, const int* in_sizes, int n_in,
                              void* d_out, int out_size, void* d_ws, size_t ws_size,
                              hipStream_t stream) {
    (void)in_sizes; (void)n_in; (void)out_size; (void)d_ws; (void)ws_size;
    hipLaunchKernelGGL(prep_kernel, dim3(1), dim3(256), 0, stream,
        d_in[0], d_in[2], d_in[3], d_in[4], d_in[5], d_in[6], d_in[7],
        d_in[8], d_in[9], d_in[10], d_in[11], d_in[12], d_in[13]);
    hipLaunchKernelGGL(ggnn_kernel, dim3(NBLK), dim3(TPB), 0, stream,
        d_in[0], d_in[1], d_out);
}

// Round 5
// 879.736 us; speedup vs baseline: 2.8017x; 1.2104x over previous
//
#include <hip/hip_runtime.h>
#include <hip/hip_bf16.h>

typedef _Float16 v8h __attribute__((ext_vector_type(8)));
typedef float    v4f __attribute__((ext_vector_type(4)));

#define NTOT  16384
#define NN    70
#define EE    3
#define SS    10
#define STEPS 5
#define NB    8
#define NPAIR (NB*NN)        // 560 active of 576
#define TPB   576            // 9 waves; waves 0-4 also run MFMA
#define NBLK  (NTOT/NB)      // 2048
#define JTOT  210            // E*N (K dim)
#define KP    224            // K padded to 7 tiles of 32
#define NCOL  80             // N dim: 8 graphs * 10 states (5 tiles of 16)
#define USTR  232            // U_T col stride in fp16 (464 B: 16B-aligned, bank-friendly)
#define CSTR  84             // Csm col stride in floats (336 B: 16B-aligned, bank-friendly)

// weight offsets (floats) inside g_w
#define OFF_WIN 0
#define OFF_BIN 300
#define OFF_WR  330
#define OFF_BR  530
#define OFF_WZ  540
#define OFF_BZ  740
#define OFF_WH  750
#define OFF_BH  950
#define OFF_WO1 960
#define OFF_BO1 1070
#define OFF_WO2 1080
#define OFF_BO2 1090
#define NWTOT   1091

__device__ float g_w[NWTOT + 1];
__device__ int   g_flag;

__device__ __forceinline__ float fast_sigmoid(float x) {
    return __builtin_amdgcn_rcpf(1.0f + __expf(-x));
}
__device__ __forceinline__ float fast_tanh(float x) {
    float ax = fabsf(x);
    float e  = __expf(-2.0f * ax);
    float t  = (1.0f - e) * __builtin_amdgcn_rcpf(1.0f + e);
    return copysignf(t, x);
}

struct __align__(16) Smem {
    union {
        _Float16 Astage[80*KP];                       // 35840 B (A as fp16, step-invariant)
        struct {
            _Float16 U[NCOL*USTR];                    // 37120 B: U_T[col=(g,s)][k=j]
            float    C[NCOL*CSTR];                    // 26880 B: Csm[col][node]
        } s;
    } u;
};
// sizeof = 64000 B -> 2 blocks/CU

// ---- prep: probe dtype once, convert all weights to fp32 in g_w ----
__global__ void prep_kernel(const void* annv,
    const void* s0, const void* s1, const void* s2, const void* s3,
    const void* s4, const void* s5, const void* s6, const void* s7,
    const void* s8, const void* s9, const void* s10, const void* s11)
{
    __shared__ int sflag;
    if (threadIdx.x == 0) {
        const unsigned short* u = (const unsigned short*)annv;
        int good = 0;
        for (int k = 0; k < 128; ++k) {
            unsigned short bb = u[k];
            int ex = (bb >> 7) & 0xFF;
            if (bb == 0 || (ex >= 101 && ex <= 131)) ++good;
        }
        sflag = (good >= 112) ? 1 : 0;
        g_flag = sflag;
    }
    __syncthreads();
    const int f = sflag;
    const void* srcs[12] = {s0,s1,s2,s3,s4,s5,s6,s7,s8,s9,s10,s11};
    const int offs[12] = {OFF_WIN,OFF_BIN,OFF_WR,OFF_BR,OFF_WZ,OFF_BZ,
                          OFF_WH,OFF_BH,OFF_WO1,OFF_BO1,OFF_WO2,OFF_BO2};
    const int cnts[12] = {300,30,200,10,200,10,200,10,110,10,10,1};
    for (int a = 0; a < 12; ++a)
        for (int k = threadIdx.x; k < cnts[a]; k += blockDim.x)
            g_w[offs[a] + k] = f ? (float)((const __hip_bfloat16*)srcs[a])[k]
                                 : ((const float*)srcs[a])[k];
}

template<typename T>
__device__ __forceinline__ void run_impl(const void* annv, const void* Av,
                                         void* outv, Smem& sm)
{
    const T* ann_g = (const T*)annv;
    const T* A_g   = (const T*)Av;
    T* out_g       = (T*)outv;
    const int tid  = threadIdx.x;
    const int blk  = blockIdx.x;
    const int w    = tid >> 6;      // wave id 0..8
    const int lane = tid & 63;
    const float* __restrict__ gw = g_w;

    // ---- stage A into LDS as fp16 (k-pad zeroed): A[n][j] -> Astage[n*KP + j]
    for (int idx = tid; idx < NN*KP; idx += TPB) {
        const int n2 = idx / KP;
        const int j  = idx - n2*KP;
        sm.u.Astage[idx] = (j < JTOT) ? (_Float16)(float)A_g[n2*JTOT + j] : (_Float16)0.f;
    }
    __syncthreads();

    // ---- preload A fragments (step-invariant): wave w owns M-tile w (nodes 16w..16w+15)
    // A-frag layout (16x16x32): lane holds A[m=lane&15][k=(lane>>4)*8 + j], j=0..7
    v8h a_frag[7];
    {
        const int m  = w*16 + (lane & 15);
        const int mr = (m < NN) ? m : 0;
        const int q  = lane >> 4;
        const _Float16* As = &sm.u.Astage[mr*KP + q*8];
        const v8h zero8 = {0,0,0,0,0,0,0,0};
        #pragma unroll
        for (int kt = 0; kt < 7; ++kt)
            a_frag[kt] = (w < 5 && m < NN) ? *(const v8h*)(As + kt*32) : zero8;
    }
    __syncthreads();   // A-frags read before U overwrites Astage region

    // ---- zero U_T k-pad rows (k=210..223) once; MFMA pads multiply clean zeros
    for (int idx = tid; idx < NCOL*14; idx += TPB) {
        const int c = idx / 14, k = JTOT + (idx - c*14);
        sm.u.s.U[c*USTR + k] = (_Float16)0.f;
    }

    const int g   = tid / NN;            // graph 0..7 (8 for tail threads)
    const int n   = tid - g*NN;          // node 0..69
    const int b   = blk*NB + g;
    const bool act = (tid < NPAIR);

    float ann = 0.f;
    float pr[SS];
    #pragma unroll
    for (int s = 0; s < SS; ++s) pr[s] = 0.f;
    if (act) { ann = (float)ann_g[b*NN + n]; pr[0] = ann; }

    #pragma unroll 1
    for (int step = 0; step < STEPS; ++step) {
        // ---- U-build: thread (g,n) writes ins rows j=e*70+n for its graph
        if (act) {
            _Float16* uw = &sm.u.s.U[(g*SS)*USTR + n];
            #pragma unroll
            for (int e = 0; e < EE; ++e)
                #pragma unroll
                for (int s = 0; s < SS; ++s) {
                    float uv = gw[OFF_BIN + e*SS + s];
                    #pragma unroll
                    for (int t = 0; t < SS; ++t)
                        uv += gw[OFF_WIN + e*100 + s*SS + t] * pr[t];
                    uw[s*USTR + e*NN] = (_Float16)uv;
                }
        }
        __syncthreads();   // U complete before B-frag reads

        // ---- MFMA: waves 0-4, wave w -> M-tile w, all 5 N-tiles, K=7 tiles of 32
        if (w < 5) {
            const int c = lane & 15, q = lane >> 4;
            #pragma unroll
            for (int nt = 0; nt < 5; ++nt) {
                v4f acc = {0.f, 0.f, 0.f, 0.f};
                const _Float16* Ub = &sm.u.s.U[(nt*16 + c)*USTR + q*8];
                #pragma unroll
                for (int kt = 0; kt < 7; ++kt) {
                    v8h bfrag = *(const v8h*)(Ub + kt*32);
                    acc = __builtin_amdgcn_mfma_f32_16x16x32_f16(a_frag[kt], bfrag, acc, 0, 0, 0);
                }
                // C-frag: lane holds C[rows m0..m0+3][col]; write b128 to Csm[col][m0..m0+3]
                float* cwp = &sm.u.s.C[(nt*16 + c)*CSTR + w*16 + q*4];
                *(v4f*)cwp = acc;
            }
        }
        __syncthreads();   // C complete before gate reads

        // ---- gates
        if (act) {
            float ai[SS];
            const float* cr = &sm.u.s.C[(g*SS)*CSTR + n];
            #pragma unroll
            for (int s = 0; s < SS; ++s) ai[s] = cr[s*CSTR];

            float rp[SS], hh[SS];
            #pragma unroll
            for (int s = 0; s < SS; ++s) {
                float acc = gw[OFF_BR+s];
                #pragma unroll
                for (int d = 0; d < SS; ++d) acc += ai[d]*gw[OFF_WR + s*2*SS + d];
                #pragma unroll
                for (int d = 0; d < SS; ++d) acc += pr[d]*gw[OFF_WR + s*2*SS + SS + d];
                rp[s] = fast_sigmoid(acc) * pr[s];   // r * prop
            }
            #pragma unroll
            for (int s = 0; s < SS; ++s) {
                float acc = gw[OFF_BH+s];
                #pragma unroll
                for (int d = 0; d < SS; ++d) acc += ai[d]*gw[OFF_WH + s*2*SS + d];
                #pragma unroll
                for (int d = 0; d < SS; ++d) acc += rp[d]*gw[OFF_WH + s*2*SS + SS + d];
                hh[s] = fast_tanh(acc);
            }
            #pragma unroll
            for (int s = 0; s < SS; ++s) {
                float acc = gw[OFF_BZ+s];
                #pragma unroll
                for (int d = 0; d < SS; ++d) acc += ai[d]*gw[OFF_WZ + s*2*SS + d];
                #pragma unroll
                for (int d = 0; d < SS; ++d) acc += pr[d]*gw[OFF_WZ + s*2*SS + SS + d];
                const float z = fast_sigmoid(acc);
                pr[s] += z*(hh[s]-pr[s]);
            }
        }
        // no barrier needed here: next U-build writes U_T (disjoint from Csm),
        // and barrier above already ordered this step's B-frag reads.
    }

    // ---- epilogue: out = tanh([prop, ann] @ Wo1^T + bo1) @ Wo2^T + bo2
    if (act) {
        float o = gw[OFF_BO2];
        #pragma unroll
        for (int s = 0; s < SS; ++s) {
            float acc = gw[OFF_BO1+s] + ann*gw[OFF_WO1 + s*(SS+1) + SS];
            #pragma unroll
            for (int d = 0; d < SS; ++d) acc += pr[d]*gw[OFF_WO1 + s*(SS+1) + d];
            o += fast_tanh(acc) * gw[OFF_WO2 + s];
        }
        out_g[b*NN + n] = (T)o;
    }
}

__global__ __launch_bounds__(TPB, 5)   // VGPR cap 102; est. live ~85 -> 2 blocks/CU
void ggnn_kernel(const void* annv, const void* Av, void* outv)
{
    __shared__ Smem sm;
    if (g_flag)
        run_impl<__hip_bfloat16>(annv, Av, outv, sm);
    else
        run_impl<float>(annv, Av, outv, sm);
}

extern "C" void kernel_launch(void* const* d_in, const int* in_sizes, int n_in,
                              void* d_out, int out_size, void* d_ws, size_t ws_size,
                              hipStream_t stream) {
    (void)in_sizes; (void)n_in; (void)out_size; (void)d_ws; (void)ws_size;
    hipLaunchKernelGGL(prep_kernel, dim3(1), dim3(256), 0, stream,
        d_in[0], d_in[2], d_in[3], d_in[4], d_in[5], d_in[6], d_in[7],
        d_in[8], d_in[9], d_in[10], d_in[11], d_in[12], d_in[13]);
    hipLaunchKernelGGL(ggnn_kernel, dim3(NBLK), dim3(TPB), 0, stream,
        d_in[0], d_in[1], d_out);
}